// Round 14
// baseline (130.976 us; speedup 1.0000x reference)
//
#include <hip/hip_runtime.h>
#include <cstdint>
#include <cstddef>

// Problem constants: B=2, S=2048, E=1024, H=16, D=64
typedef unsigned short u16;
typedef unsigned int u32;
typedef __attribute__((ext_vector_type(8))) short bf16x8;   // 8 bf16 = 4 VGPRs (MFMA A/B frag)
typedef __attribute__((ext_vector_type(4))) float f32x4;    // 16x16 MFMA C/D frag
typedef __attribute__((ext_vector_type(16))) float f32x16;  // 32x32 MFMA C/D frag
typedef __attribute__((ext_vector_type(4))) u16 u16x4;
typedef __attribute__((ext_vector_type(4))) u32 u32x4;
typedef __attribute__((ext_vector_type(2))) u32 u32x2;

__device__ __forceinline__ u16 f2bf(float f) {
  u32 x = __builtin_bit_cast(u32, f);
  x += 0x7fffu + ((x >> 16) & 1u);   // RNE
  return (u16)(x >> 16);
}

// async global->LDS, 16B per lane; LDS dest is wave-uniform base + lane*16
__device__ __forceinline__ void g2lds16(const u16* g, u16* l) {
  __builtin_amdgcn_global_load_lds(
      (const __attribute__((address_space(1))) u32*)g,
      (__attribute__((address_space(3))) u32*)l, 16, 0, 0);
}

// ---------------- fp32 -> bf16 convert (7 arrays) ----------------
struct CvtArgs { const float* s[7]; u16* d[7]; int n4[7]; };

__global__ __launch_bounds__(256) void cvt_all(CvtArgs a) {
  int y = blockIdx.y;
  const float4* __restrict__ src = (const float4*)a.s[y];
  u16* __restrict__ dst = a.d[y];
  int n4 = a.n4[y];
  for (int i = blockIdx.x * blockDim.x + threadIdx.x; i < n4;
       i += gridDim.x * blockDim.x) {
    float4 v = src[i];
    u16x4 o = { f2bf(v.x), f2bf(v.y), f2bf(v.z), f2bf(v.w) };
    *(u16x4*)(dst + (size_t)i * 4) = o;
  }
}

// ---------------- bf16 GEMM, C = A[M,K] * W[N,K]^T + bias ----------------
// 128x128 tile, BK=32, 4 waves, dbuf LDS with COUNTED vmcnt (depth-2).
// XCD-aware swizzle (bijective 8x32 transpose of the per-z linear id).
struct GemmArgs {
  const u16* A[3]; const u16* W[3]; const float* bias[3];
  void* out[3]; float scale[3]; int mode[3];
};

__global__ __launch_bounds__(256) void gemm_fused(GemmArgs ga) {
  __shared__ alignas(16) u16 As[2][128 * 32];
  __shared__ alignas(16) u16 Bs[2][128 * 32];
  const int z = blockIdx.z;
  const u16* __restrict__ A = ga.A[z];
  const u16* __restrict__ W = ga.W[z];
  const int tid = threadIdx.x;
  const int lane = tid & 63;
  const int w = tid >> 6;
  const int lo4 = lane & 15, hi2 = lane >> 4;
  const int l = (int)blockIdx.x + 8 * (int)blockIdx.y;  // 0..255 per z
  const int wl = (l & 7) * 32 + (l >> 3);               // bijective transpose
  const int m0 = (wl >> 3) * 128;
  const int n0 = (wl & 7) * 128;
  const int wr = w >> 1, wc = w & 1;

  f32x4 acc[4][4] = {};

  auto stage = [&](int kt, int buf) {
    const int k0 = kt * 32;
#pragma unroll
    for (int i = 0; i < 2; ++i) {
      int c = (i * 4 + w) * 64 + lane;        // 16B chunk id, 512 chunks/tile
      int r = c >> 2;                         // tile row (4 chunks per 64B row)
      int q = (c & 3) ^ ((r >> 1) & 3);       // inverse swizzle on source
      g2lds16(A + (size_t)(m0 + r) * 1024 + k0 + q * 8, As[buf] + (i * 4 + w) * 512);
      g2lds16(W + (size_t)(n0 + r) * 1024 + k0 + q * 8, Bs[buf] + (i * 4 + w) * 512);
    }
  };

  stage(0, 0);                                // depth-2 prologue
  stage(1, 1);
  for (int kt = 0; kt < 32; ++kt) {           // K = 1024, BK = 32
    const int cur = kt & 1;
    asm volatile("s_waitcnt vmcnt(4)" ::: "memory");  // tile kt's 4 landed
    __builtin_amdgcn_s_barrier();                     // landed for ALL waves
    bf16x8 af[4], bfr[4];
#pragma unroll
    for (int i = 0; i < 4; ++i) {
      int r = wr * 64 + i * 16 + lo4;
      int q = hi2 ^ ((r >> 1) & 3);
      af[i] = *(const bf16x8*)(As[cur] + r * 32 + q * 8);
    }
#pragma unroll
    for (int j = 0; j < 4; ++j) {
      int r = wc * 64 + j * 16 + lo4;
      int q = hi2 ^ ((r >> 1) & 3);
      bfr[j] = *(const bf16x8*)(Bs[cur] + r * 32 + q * 8);
    }
#pragma unroll
    for (int i = 0; i < 4; ++i)
#pragma unroll
      for (int j = 0; j < 4; ++j)
        acc[i][j] = __builtin_amdgcn_mfma_f32_16x16x32_bf16(af[i], bfr[j], acc[i][j], 0, 0, 0);
    __builtin_amdgcn_s_barrier();             // all waves done reading buf cur
    stage(kt + 2 < 32 ? kt + 2 : kt, cur);    // tail: dummy keeps counts uniform
  }
  asm volatile("s_waitcnt vmcnt(0)" ::: "memory");  // drain before LDS freed

  const float* __restrict__ bias = ga.bias[z];
  const float cs = ga.scale[z];
  const int mode = ga.mode[z];
#pragma unroll
  for (int j = 0; j < 4; ++j) {
    int n = n0 + wc * 64 + j * 16 + lo4;
    float bv = bias[n];
#pragma unroll
    for (int i = 0; i < 4; ++i) {
#pragma unroll
      for (int rg = 0; rg < 4; ++rg) {
        int m = m0 + wr * 64 + i * 16 + hi2 * 4 + rg;  // C: col=lane&15, row=(lane>>4)*4+reg
        float v = (acc[i][j][rg] + bv) * cs;
        if (mode == 2) {
          ((float*)ga.out[z])[(size_t)m * 1024 + n] = v;
        } else {
          int b = m >> 11, s = m & 2047, h = n >> 6, d = n & 63;
          size_t addr = (mode == 0)
            ? ((size_t)(b * 16 + h) * 2048 + s) * 64 + d    // [B,H,S,D]
            : ((size_t)(b * 16 + h) * 64 + d) * 2048 + s;   // [B,H,D,S]
          ((u16*)ga.out[z])[addr] = f2bf(v);
        }
      }
    }
  }
}

// ---------------- flash attention: uniform-work 8-wave, 2-sub reuse -------
// grid (8, 32) = 256 blocks = 1/CU, 512 threads = 4 KV-GROUPS x 2 waves.
// R12 structure with the register cliff removed: __launch_bounds__(512)
// WITHOUT a min-waves arg (R12's ",2" halved the VGPR cap to 128 and spilled
// the 8 live f32x16; the 512-thread shape already implies 2 waves/SIMD ->
// 256-reg cap, enough for ~200 live).
// UNIFORM WORK: block (slot, bh) runs qt=slot then qt=15-slot -> exactly
// 33 KV-tile-units per block; 8 waves/CU sustained.
// 2-SUB REUSE (R6, +15%): wave (wg,wv) owns 64 q-rows as two 32-row subs;
// each K/V-frag LDS read feeds TWO MFMAs -> LDS bytes per MFMA halved.
// XCD head-locality (R9, FETCH 12 MB): xcd = bx owns heads bh = bx*4+(by>>3).
// Causal: wave needs tiles jt <= 2qt+wv -> nt_w = 2qt+wv+1; mask only at
// jt == nt_w-1.  Counted vmcnt(8) depth-2; dummy tail stages.
// Merge: 3 sequential LDS rounds, stride-65/5 padded (R13's 3.5M bank
// conflicts came from the old stride-64 merge layout: all lanes -> 1 bank).
// Swapped QK^T; softmax in-register; PV via cvt_pk+permlane32_swap (T12);
// defer-max (T13).  Q pre-scaled by D^-0.5*log2(e) => P = exp2(S - m).
__global__ __launch_bounds__(512) void attn_kernel(
    const u16* __restrict__ Q, const u16* __restrict__ K,
    const u16* __restrict__ Vt, u16* __restrict__ Out,
    const int* __restrict__ causal_p) {
  __shared__ alignas(16) u16 Ks[4][2][64 * 64];   // 64 KB
  __shared__ alignas(16) u16 Vs[4][2][64 * 64];   // 64 KB
  __shared__ float ml2[640];                      // merge stats, stride 5
  const int tid = threadIdx.x, lane = tid & 63, w = tid >> 6;   // w in 0..7
  const int wg = w >> 1, wv = w & 1;              // 4 groups x 2 waves
  const int ql = lane & 31, hi = lane >> 5;
  const int bx = (int)blockIdx.x, by = (int)blockIdx.y;
  const int bh = bx * 4 + (by >> 3);              // 4 heads per XCD (xcd=bx)
  const int slot = by & 7;
  const int causal = *causal_p;
  const u16* Qb = Q + (size_t)bh * 2048 * 64;     // [S][D]
  const u16* Kb = K + (size_t)bh * 2048 * 64;     // [S][D]
  const u16* Vb = Vt + (size_t)bh * 64 * 2048;    // [D][S]
  const int batch = bh >> 4, h = bh & 15;

  // group-local staging: group's 2 waves stage K,V tile jt (8 ld/thread)
  auto stageKV = [&](int jt, int buf) {
#pragma unroll
    for (int i = 0; i < 4; ++i) {
      int c = i * 128 + wv * 64 + lane;
      int r = c >> 3;
      int q = (c & 7) ^ (r & 7);
      g2lds16(Kb + (size_t)(jt * 64 + r) * 64 + q * 8, Ks[wg][buf] + (i * 128 + wv * 64) * 8);
      g2lds16(Vb + (size_t)r * 2048 + jt * 64 + q * 8, Vs[wg][buf] + (i * 128 + wv * 64) * 8);
    }
  };

  auto online_sm = [&](f32x16& s0, f32x16& s1, float& m_r, float& l_r,
                       f32x16& o0, f32x16& o1) {
    float pm = fmaxf(s0[0], s1[0]);
#pragma unroll
    for (int rg = 1; rg < 16; ++rg) pm = fmaxf(pm, fmaxf(s0[rg], s1[rg]));
    pm = fmaxf(pm, __shfl_xor(pm, 32));
    if (!__all(pm <= m_r + 8.f)) {            // defer-max
      float mn = fmaxf(m_r, pm);
      float corr = exp2f(m_r - mn);
      m_r = mn; l_r *= corr;
#pragma unroll
      for (int rg = 0; rg < 16; ++rg) { o0[rg] *= corr; o1[rg] *= corr; }
    }
    float sum = 0.f;
#pragma unroll
    for (int rg = 0; rg < 16; ++rg) { s0[rg] = exp2f(s0[rg] - m_r); sum += s0[rg]; }
#pragma unroll
    for (int rg = 0; rg < 16; ++rg) { s1[rg] = exp2f(s1[rg] - m_r); sum += s1[rg]; }
    sum += __shfl_xor(sum, 32);
    l_r += sum;
  };

  float* Od = (float*)&Ks[0][0][0];            // merge region (stride 65)
  const int li = wv * 64 + lane;               // 0..127

  for (int seg = 0; seg < 2; ++seg) {
    const int qt = seg ? 15 - slot : slot;     // paired: 33 tile-units/block
    const int qA = qt * 128 + wv * 64 + ql;    // sub A q-row
    const int qB = qA + 32;                    // sub B q-row

    bf16x8 qfA[4], qfB[4];
#pragma unroll
    for (int dsl = 0; dsl < 4; ++dsl) {
      qfA[dsl] = *(const bf16x8*)(Qb + (size_t)qA * 64 + dsl * 16 + hi * 8);
      qfB[dsl] = *(const bf16x8*)(Qb + (size_t)qB * 64 + dsl * 16 + hi * 8);
    }

    const int nt_w = causal ? (2 * qt + wv + 1) : 32;   // tiles this wave needs
    const int U = causal ? ((2 * qt + 5) >> 2) : 8;     // block-uniform iters

    stageKV(wg, 0);                            // depth-2 prologue
    stageKV(wg + 4, 1);

    float mA = -1e30f, lA = 0.f, mB = -1e30f, lB = 0.f;
    f32x16 oA0 = {}, oA1 = {}, oB0 = {}, oB1 = {};

    for (int u = 0; u < U; ++u) {
      const int jt = 4 * u + wg;
      const int cur = u & 1;
      asm volatile("s_waitcnt vmcnt(8)" ::: "memory");  // tile jt's 8 landed
      __builtin_amdgcn_s_barrier();                     // landed for ALL waves

      if (jt < nt_w) {
        f32x16 sA0 = {}, sA1 = {}, sB0 = {}, sB1 = {};
#pragma unroll
        for (int dsl = 0; dsl < 4; ++dsl) {
          int cc = dsl * 2 + hi;
          bf16x8 k0 = *(const bf16x8*)(Ks[wg][cur] + ql * 64 + ((cc ^ (ql & 7)) * 8));
          bf16x8 k1 = *(const bf16x8*)(Ks[wg][cur] + (32 + ql) * 64 + ((cc ^ (ql & 7)) * 8));
          sA0 = __builtin_amdgcn_mfma_f32_32x32x16_bf16(k0, qfA[dsl], sA0, 0, 0, 0);
          sB0 = __builtin_amdgcn_mfma_f32_32x32x16_bf16(k0, qfB[dsl], sB0, 0, 0, 0);
          sA1 = __builtin_amdgcn_mfma_f32_32x32x16_bf16(k1, qfA[dsl], sA1, 0, 0, 0);
          sB1 = __builtin_amdgcn_mfma_f32_32x32x16_bf16(k1, qfB[dsl], sB1, 0, 0, 0);
        }

        if (causal && jt == nt_w - 1) {        // this wave's diagonal tile
#pragma unroll
          for (int rg = 0; rg < 16; ++rg) {
            int kof = jt * 64 + 8 * (rg >> 2) + (rg & 3) + 4 * hi;
            sA0[rg] = (kof > qA) ? -1e30f : sA0[rg];
            sA1[rg] = (kof + 32 > qA) ? -1e30f : sA1[rg];
            sB0[rg] = (kof > qB) ? -1e30f : sB0[rg];
            sB1[rg] = (kof + 32 > qB) ? -1e30f : sB1[rg];
          }
        }

        online_sm(sA0, sA1, mA, lA, oA0, oA1);
        online_sm(sB0, sB1, mB, lB, oB0, oB1);

#pragma unroll
        for (int s = 0; s < 4; ++s) {
          const f32x16& pA = (s >= 2) ? sA1 : sA0;
          const f32x16& pB = (s >= 2) ? sB1 : sB0;
          const int base = 8 * (s & 1);
          u32 a0, a1, b0, b1, c0, c1, d0_, d1;
          asm("v_cvt_pk_bf16_f32 %0, %1, %2" : "=v"(a0) : "v"(pA[base + 0]), "v"(pA[base + 1]));
          asm("v_cvt_pk_bf16_f32 %0, %1, %2" : "=v"(a1) : "v"(pA[base + 2]), "v"(pA[base + 3]));
          asm("v_cvt_pk_bf16_f32 %0, %1, %2" : "=v"(b0) : "v"(pA[base + 4]), "v"(pA[base + 5]));
          asm("v_cvt_pk_bf16_f32 %0, %1, %2" : "=v"(b1) : "v"(pA[base + 6]), "v"(pA[base + 7]));
          asm volatile("v_permlane32_swap_b32 %0, %1" : "+v"(a0), "+v"(b0));
          asm volatile("v_permlane32_swap_b32 %0, %1" : "+v"(a1), "+v"(b1));
          asm("v_cvt_pk_bf16_f32 %0, %1, %2" : "=v"(c0) : "v"(pB[base + 0]), "v"(pB[base + 1]));
          asm("v_cvt_pk_bf16_f32 %0, %1, %2" : "=v"(c1) : "v"(pB[base + 2]), "v"(pB[base + 3]));
          asm("v_cvt_pk_bf16_f32 %0, %1, %2" : "=v"(d0_) : "v"(pB[base + 4]), "v"(pB[base + 5]));
          asm("v_cvt_pk_bf16_f32 %0, %1, %2" : "=v"(d1) : "v"(pB[base + 6]), "v"(pB[base + 7]));
          asm volatile("v_permlane32_swap_b32 %0, %1" : "+v"(c0), "+v"(d0_));
          asm volatile("v_permlane32_swap_b32 %0, %1" : "+v"(c1), "+v"(d1));
          u32x4 pwA = {a0, a1, b0, b1};
          u32x4 pwB = {c0, c1, d0_, d1};
          bf16x8 pfA = __builtin_bit_cast(bf16x8, pwA);
          bf16x8 pfB = __builtin_bit_cast(bf16x8, pwB);
#pragma unroll
          for (int df = 0; df < 2; ++df) {
            int rr = df * 32 + ql;
            bf16x8 vf = *(const bf16x8*)(Vs[wg][cur] + rr * 64 + (((s * 2 + hi) ^ (rr & 7)) * 8));
            if (df) {
              oA1 = __builtin_amdgcn_mfma_f32_32x32x16_bf16(vf, pfA, oA1, 0, 0, 0);
              oB1 = __builtin_amdgcn_mfma_f32_32x32x16_bf16(vf, pfB, oB1, 0, 0, 0);
            } else {
              oA0 = __builtin_amdgcn_mfma_f32_32x32x16_bf16(vf, pfA, oA0, 0, 0, 0);
              oB0 = __builtin_amdgcn_mfma_f32_32x32x16_bf16(vf, pfB, oB0, 0, 0, 0);
            }
          }
        }
      }
      __builtin_amdgcn_s_barrier();            // all waves done reading buf
      stageKV(u + 2 < U ? 4 * (u + 2) + wg : jt, cur);  // dummy in tail
    }
    asm volatile("s_waitcnt vmcnt(0)" ::: "memory");    // drain before reuse
    __syncthreads();

    // ---- merge the 4 groups' partials: 3 sequential LDS rounds ----
    // stride-65 layout: bank = (li*65 + idx) % 32 = (li + idx) % 32 ->
    // consecutive lanes hit consecutive banks (conflict-free).
    auto store_partial = [&]() {
#pragma unroll
      for (int rg = 0; rg < 16; ++rg) {
        Od[li * 65 + rg]      = oA0[rg];
        Od[li * 65 + 16 + rg] = oA1[rg];
        Od[li * 65 + 32 + rg] = oB0[rg];
        Od[li * 65 + 48 + rg] = oB1[rg];
      }
      ml2[li * 5 + 0] = mA; ml2[li * 5 + 1] = lA;
      ml2[li * 5 + 2] = mB; ml2[li * 5 + 3] = lB;
    };
    auto merge_partial = [&]() {
      float m_b = ml2[li * 5 + 0], l_b = ml2[li * 5 + 1];
      float mn = fmaxf(mA, m_b);
      float ca = exp2f(mA - mn), cb = exp2f(m_b - mn);
      mA = mn; lA = lA * ca + l_b * cb;
#pragma unroll
      for (int rg = 0; rg < 16; ++rg) {
        oA0[rg] = oA0[rg] * ca + Od[li * 65 + rg] * cb;
        oA1[rg] = oA1[rg] * ca + Od[li * 65 + 16 + rg] * cb;
      }
      m_b = ml2[li * 5 + 2]; l_b = ml2[li * 5 + 3];
      mn = fmaxf(mB, m_b);
      ca = exp2f(mB - mn); cb = exp2f(m_b - mn);
      mB = mn; lB = lB * ca + l_b * cb;
#pragma unroll
      for (int rg = 0; rg < 16; ++rg) {
        oB0[rg] = oB0[rg] * ca + Od[li * 65 + 32 + rg] * cb;
        oB1[rg] = oB1[rg] * ca + Od[li * 65 + 48 + rg] * cb;
      }
    };

    if (wg == 1) store_partial();
    __syncthreads();
    if (wg == 0) merge_partial();
    __syncthreads();
    if (wg == 2) store_partial();
    __syncthreads();
    if (wg == 0) merge_partial();
    __syncthreads();
    if (wg == 3) store_partial();
    __syncthreads();

    if (wg == 0) {
      merge_partial();
#pragma unroll
      for (int sub = 0; sub < 2; ++sub) {
        float rl = 1.f / (sub ? lB : lA);
        int qrow = sub ? qB : qA;
        u16* orow = Out + ((size_t)(batch * 2048 + qrow)) * 1024 + h * 64;
#pragma unroll
        for (int df = 0; df < 2; ++df) {
          const f32x16& oo = sub ? (df ? oB1 : oB0) : (df ? oA1 : oA0);
#pragma unroll
          for (int b2 = 0; b2 < 4; ++b2) {
            u32 w0, w1;
            float v0 = oo[4 * b2 + 0] * rl, v1 = oo[4 * b2 + 1] * rl;
            float v2 = oo[4 * b2 + 2] * rl, v3 = oo[4 * b2 + 3] * rl;
            asm("v_cvt_pk_bf16_f32 %0, %1, %2" : "=v"(w0) : "v"(v0), "v"(v1));
            asm("v_cvt_pk_bf16_f32 %0, %1, %2" : "=v"(w1) : "v"(v2), "v"(v3));
            int d0 = df * 32 + b2 * 8 + hi * 4;   // d = 32df + 8b2 + 4hi + e
            u32x2 pr = {w0, w1};
            *(u32x2*)(orow + d0) = pr;
          }
        }
      }
    }
    __syncthreads();                           // merge reads done before next
  }
}

// ---------------- launch ----------------
extern "C" void kernel_launch(void* const* d_in, const int* in_sizes, int n_in,
                              void* d_out, int out_size, void* d_ws, size_t ws_size,
                              hipStream_t stream) {
  (void)in_sizes; (void)n_in; (void)out_size; (void)ws_size;
  const float* query = (const float*)d_in[0];
  const float* key   = (const float*)d_in[1];
  const float* value = (const float*)d_in[2];
  const float* Wq = (const float*)d_in[3];
  const float* bq = (const float*)d_in[4];
  const float* Wk = (const float*)d_in[5];
  const float* bk = (const float*)d_in[6];
  const float* Wv = (const float*)d_in[7];
  const float* bv = (const float*)d_in[8];
  const float* Wo = (const float*)d_in[9];
  const float* bo = (const float*)d_in[10];
  const int* is_causal = (const int*)d_in[11];

  u16* wsp = (u16*)d_ws;                 // ~64 MB of scratch used
  u16* xq  = wsp;                        // 4M elems bf16 [4096,1024]
  u16* xk  = xq  + (4u << 20);
  u16* xv  = xk  + (4u << 20);
  u16* wq  = xv  + (4u << 20);           // 1M elems bf16 [1024,1024]
  u16* wk  = wq  + (1u << 20);
  u16* wv  = wk  + (1u << 20);
  u16* wo  = wv  + (1u << 20);
  u16* Qb  = wo  + (1u << 20);           // 4M, [B,H,S,D], pre-scaled
  u16* Kb  = Qb  + (4u << 20);           // 4M, [B,H,S,D]
  u16* Vtb = Kb  + (4u << 20);           // 4M, [B,H,D,S]
  u16* attn= Vtb + (4u << 20);           // 4M, [B,S,E]

  CvtArgs ca;
  ca.s[0] = query; ca.d[0] = xq; ca.n4[0] = 1 << 20;
  ca.s[1] = key;   ca.d[1] = xk; ca.n4[1] = 1 << 20;
  ca.s[2] = value; ca.d[2] = xv; ca.n4[2] = 1 << 20;
  ca.s[3] = Wq; ca.d[3] = wq; ca.n4[3] = 1 << 18;
  ca.s[4] = Wk; ca.d[4] = wk; ca.n4[4] = 1 << 18;
  ca.s[5] = Wv; ca.d[5] = wv; ca.n4[5] = 1 << 18;
  ca.s[6] = Wo; ca.d[6] = wo; ca.n4[6] = 1 << 18;
  cvt_all<<<dim3(512, 7), 256, 0, stream>>>(ca);

  const float LOG2E = 1.4426950408889634f;
  GemmArgs g1;
  g1.A[0] = xq; g1.W[0] = wq; g1.bias[0] = bq; g1.out[0] = Qb;
  g1.scale[0] = 0.125f * LOG2E; g1.mode[0] = 0;   // Q pre-scaled into exp2 domain
  g1.A[1] = xk; g1.W[1] = wk; g1.bias[1] = bk; g1.out[1] = Kb;
  g1.scale[1] = 1.f; g1.mode[1] = 0;
  g1.A[2] = xv; g1.W[2] = wv; g1.bias[2] = bv; g1.out[2] = Vtb;
  g1.scale[2] = 1.f; g1.mode[2] = 1;              // V stored transposed
  gemm_fused<<<dim3(8, 32, 3), 256, 0, stream>>>(g1);

  attn_kernel<<<dim3(8, 32), 512, 0, stream>>>(Qb, Kb, Vtb, attn, is_causal);

  GemmArgs g2;
  for (int i = 0; i < 3; ++i) {
    g2.A[i] = attn; g2.W[i] = wo; g2.bias[i] = bo; g2.out[i] = d_out;
    g2.scale[i] = 1.f; g2.mode[i] = 2;
  }
  gemm_fused<<<dim3(8, 32, 1), 256, 0, stream>>>(g2);
}

// Round 15
// 127.434 us; speedup vs baseline: 1.0278x; 1.0278x over previous
//
#include <hip/hip_runtime.h>
#include <cstdint>
#include <cstddef>

// Problem constants: B=2, S=2048, E=1024, H=16, D=64
typedef unsigned short u16;
typedef unsigned int u32;
typedef __attribute__((ext_vector_type(8))) short bf16x8;   // 8 bf16 = 4 VGPRs (MFMA A/B frag)
typedef __attribute__((ext_vector_type(4))) float f32x4;    // 16x16 MFMA C/D frag
typedef __attribute__((ext_vector_type(16))) float f32x16;  // 32x32 MFMA C/D frag
typedef __attribute__((ext_vector_type(4))) u16 u16x4;
typedef __attribute__((ext_vector_type(4))) u32 u32x4;
typedef __attribute__((ext_vector_type(2))) u32 u32x2;

__device__ __forceinline__ u16 f2bf(float f) {
  u32 x = __builtin_bit_cast(u32, f);
  x += 0x7fffu + ((x >> 16) & 1u);   // RNE
  return (u16)(x >> 16);
}

// async global->LDS, 16B per lane; LDS dest is wave-uniform base + lane*16
__device__ __forceinline__ void g2lds16(const u16* g, u16* l) {
  __builtin_amdgcn_global_load_lds(
      (const __attribute__((address_space(1))) u32*)g,
      (__attribute__((address_space(3))) u32*)l, 16, 0, 0);
}

// ---------------- fp32 -> bf16 convert (7 arrays) ----------------
struct CvtArgs { const float* s[7]; u16* d[7]; int n4[7]; };

__global__ __launch_bounds__(256) void cvt_all(CvtArgs a) {
  int y = blockIdx.y;
  const float4* __restrict__ src = (const float4*)a.s[y];
  u16* __restrict__ dst = a.d[y];
  int n4 = a.n4[y];
  for (int i = blockIdx.x * blockDim.x + threadIdx.x; i < n4;
       i += gridDim.x * blockDim.x) {
    float4 v = src[i];
    u16x4 o = { f2bf(v.x), f2bf(v.y), f2bf(v.z), f2bf(v.w) };
    *(u16x4*)(dst + (size_t)i * 4) = o;
  }
}

// ---------------- bf16 GEMM, C = A[M,K] * W[N,K]^T + bias ----------------
// 128x128 tile, BK=32, 4 waves, dbuf LDS with COUNTED vmcnt (depth-2).
// XCD-aware swizzle (bijective 8x32 transpose of the per-z linear id).
struct GemmArgs {
  const u16* A[3]; const u16* W[3]; const float* bias[3];
  void* out[3]; float scale[3]; int mode[3];
};

__global__ __launch_bounds__(256) void gemm_fused(GemmArgs ga) {
  __shared__ alignas(16) u16 As[2][128 * 32];
  __shared__ alignas(16) u16 Bs[2][128 * 32];
  const int z = blockIdx.z;
  const u16* __restrict__ A = ga.A[z];
  const u16* __restrict__ W = ga.W[z];
  const int tid = threadIdx.x;
  const int lane = tid & 63;
  const int w = tid >> 6;
  const int lo4 = lane & 15, hi2 = lane >> 4;
  const int l = (int)blockIdx.x + 8 * (int)blockIdx.y;  // 0..255 per z
  const int wl = (l & 7) * 32 + (l >> 3);               // bijective transpose
  const int m0 = (wl >> 3) * 128;
  const int n0 = (wl & 7) * 128;
  const int wr = w >> 1, wc = w & 1;

  f32x4 acc[4][4] = {};

  auto stage = [&](int kt, int buf) {
    const int k0 = kt * 32;
#pragma unroll
    for (int i = 0; i < 2; ++i) {
      int c = (i * 4 + w) * 64 + lane;        // 16B chunk id, 512 chunks/tile
      int r = c >> 2;                         // tile row (4 chunks per 64B row)
      int q = (c & 3) ^ ((r >> 1) & 3);       // inverse swizzle on source
      g2lds16(A + (size_t)(m0 + r) * 1024 + k0 + q * 8, As[buf] + (i * 4 + w) * 512);
      g2lds16(W + (size_t)(n0 + r) * 1024 + k0 + q * 8, Bs[buf] + (i * 4 + w) * 512);
    }
  };

  stage(0, 0);                                // depth-2 prologue
  stage(1, 1);
  for (int kt = 0; kt < 32; ++kt) {           // K = 1024, BK = 32
    const int cur = kt & 1;
    asm volatile("s_waitcnt vmcnt(4)" ::: "memory");  // tile kt's 4 landed
    __builtin_amdgcn_s_barrier();                     // landed for ALL waves
    bf16x8 af[4], bfr[4];
#pragma unroll
    for (int i = 0; i < 4; ++i) {
      int r = wr * 64 + i * 16 + lo4;
      int q = hi2 ^ ((r >> 1) & 3);
      af[i] = *(const bf16x8*)(As[cur] + r * 32 + q * 8);
    }
#pragma unroll
    for (int j = 0; j < 4; ++j) {
      int r = wc * 64 + j * 16 + lo4;
      int q = hi2 ^ ((r >> 1) & 3);
      bfr[j] = *(const bf16x8*)(Bs[cur] + r * 32 + q * 8);
    }
#pragma unroll
    for (int i = 0; i < 4; ++i)
#pragma unroll
      for (int j = 0; j < 4; ++j)
        acc[i][j] = __builtin_amdgcn_mfma_f32_16x16x32_bf16(af[i], bfr[j], acc[i][j], 0, 0, 0);
    __builtin_amdgcn_s_barrier();             // all waves done reading buf cur
    stage(kt + 2 < 32 ? kt + 2 : kt, cur);    // tail: dummy keeps counts uniform
  }
  asm volatile("s_waitcnt vmcnt(0)" ::: "memory");  // drain before LDS freed

  const float* __restrict__ bias = ga.bias[z];
  const float cs = ga.scale[z];
  const int mode = ga.mode[z];
#pragma unroll
  for (int j = 0; j < 4; ++j) {
    int n = n0 + wc * 64 + j * 16 + lo4;
    float bv = bias[n];
#pragma unroll
    for (int i = 0; i < 4; ++i) {
#pragma unroll
      for (int rg = 0; rg < 4; ++rg) {
        int m = m0 + wr * 64 + i * 16 + hi2 * 4 + rg;  // C: col=lane&15, row=(lane>>4)*4+reg
        float v = (acc[i][j][rg] + bv) * cs;
        if (mode == 2) {
          ((float*)ga.out[z])[(size_t)m * 1024 + n] = v;
        } else {
          int b = m >> 11, s = m & 2047, h = n >> 6, d = n & 63;
          size_t addr = (mode == 0)
            ? ((size_t)(b * 16 + h) * 2048 + s) * 64 + d    // [B,H,S,D]
            : ((size_t)(b * 16 + h) * 64 + d) * 2048 + s;   // [B,H,D,S]
          ((u16*)ga.out[z])[addr] = f2bf(v);
        }
      }
    }
  }
}

// ---------------- flash attention: uniform-work, R9 register shape --------
// grid (16, 32) = 512 blocks (= exact 2-blocks/CU capacity), 256 threads =
// 2 KV-GROUPS x 2 waves.  UNIFORM WORK via in-block segment pairing:
// QBLK=64 (32 q-tiles); block (slot, bh) runs qt=slot then qt=31-slot ->
// exactly 33 KV-tile-units per block -> 8 waves/CU SUSTAINED.
// Per-wave state ~110 VGPR (1 sub) -> no spill (R12/R14's failure mode).
// XCD head-locality (R9-proven, FETCH 12 MB): xcd = bx&7 owns heads
// bh = (bx&7)*4 + (by>>3); slot = (bx>>3)*8 + (by&7)  [bijective].
// Wave (wg,wv): rows qt*64 + wv*32 + ql; group wg handles KV tiles
// jt = 2u+wg (KVBLK=64) with its own dbuf K/V LDS (64 KB total).
// Counted vmcnt(8) depth-2; dummy tail stages keep counts uniform.
// MERGE: stride-33/3 padded layout (R14-validated: bank = (li+idx)%32,
// consecutive lanes -> consecutive banks; R13's stride-32 was ~32-way
// conflicted, 3.5M conflict cycles).
// Swapped QK^T; softmax in-register; PV via cvt_pk+permlane32_swap (T12);
// defer-max (T13).  Q pre-scaled by D^-0.5*log2(e) => P = exp2(S - m).
__global__ __launch_bounds__(256, 2) void attn_kernel(
    const u16* __restrict__ Q, const u16* __restrict__ K,
    const u16* __restrict__ Vt, u16* __restrict__ Out,
    const int* __restrict__ causal_p) {
  __shared__ alignas(16) u16 Ks[2][2][64 * 64];   // [group][buf] : 32 KB
  __shared__ alignas(16) u16 Vs[2][2][64 * 64];   // [group][buf] : 32 KB
  __shared__ float ml2[512];                      // merge stats, stride 3
  const int tid = threadIdx.x, lane = tid & 63, w = tid >> 6;   // w in 0..3
  const int wg = w >> 1, wv = w & 1;
  const int ql = lane & 31, hi = lane >> 5;
  const int bx = (int)blockIdx.x, by = (int)blockIdx.y;
  const int bh = (bx & 7) * 4 + (by >> 3);      // 4 heads per XCD (xcd=bx&7)
  const int slot = ((bx >> 3) << 3) | (by & 7); // 0..15
  const int causal = *causal_p;
  const u16* Qb = Q + (size_t)bh * 2048 * 64;   // [S][D]
  const u16* Kb = K + (size_t)bh * 2048 * 64;   // [S][D]
  const u16* Vb = Vt + (size_t)bh * 64 * 2048;  // [D][S]
  const int batch = bh >> 4, h = bh & 15;

  // group-local staging: the group's 2 waves stage K,V tile jt (8 ld/thread)
  auto stageKV = [&](int jt, int buf) {
#pragma unroll
    for (int i = 0; i < 4; ++i) {
      int c = i * 128 + wv * 64 + lane;
      int r = c >> 3;
      int q = (c & 7) ^ (r & 7);
      g2lds16(Kb + (size_t)(jt * 64 + r) * 64 + q * 8, Ks[wg][buf] + (i * 128 + wv * 64) * 8);
      g2lds16(Vb + (size_t)r * 2048 + jt * 64 + q * 8, Vs[wg][buf] + (i * 128 + wv * 64) * 8);
    }
  };

  float* Od = (float*)&Ks[0][0][0];             // merge region (stride 33)
  const int li = wv * 64 + lane;                // 0..127

  for (int seg = 0; seg < 2; ++seg) {
    const int qt = seg ? 31 - slot : slot;      // paired: 33 tile-units/block
    const int qrow = qt * 64 + wv * 32 + ql;    // this lane's q-row

    bf16x8 qf[4];
#pragma unroll
    for (int dsl = 0; dsl < 4; ++dsl)
      qf[dsl] = *(const bf16x8*)(Qb + (size_t)qrow * 64 + dsl * 16 + hi * 8);

    const int nt = causal ? (qt + 1) : 32;
    const int U = (nt + 1) >> 1;                // per group, stride 2

    stageKV(wg, 0);                             // depth-2 prologue
    stageKV(wg + 2, 1);

    float m_r = -1e30f, l_r = 0.f;
    f32x16 o0 = {}, o1 = {};

    for (int u = 0; u < U; ++u) {
      const int jt = 2 * u + wg;
      const int cur = u & 1;
      asm volatile("s_waitcnt vmcnt(8)" ::: "memory");  // tile jt's 8 landed
      __builtin_amdgcn_s_barrier();                     // landed for ALL waves

      if (jt < nt) {
        // ---- QK^T swapped: s0 = St[k=0..31][q], s1 = St[k=32..63][q]
        f32x16 s0 = {}, s1 = {};
#pragma unroll
        for (int dsl = 0; dsl < 4; ++dsl) {
          int cc = dsl * 2 + hi;
          bf16x8 k0 = *(const bf16x8*)(Ks[wg][cur] + ql * 64 + ((cc ^ (ql & 7)) * 8));
          bf16x8 k1 = *(const bf16x8*)(Ks[wg][cur] + (32 + ql) * 64 + ((cc ^ (ql & 7)) * 8));
          s0 = __builtin_amdgcn_mfma_f32_32x32x16_bf16(k0, qf[dsl], s0, 0, 0, 0);
          s1 = __builtin_amdgcn_mfma_f32_32x32x16_bf16(k1, qf[dsl], s1, 0, 0, 0);
        }

        if (causal && jt == qt) {               // diagonal tile
#pragma unroll
          for (int rg = 0; rg < 16; ++rg) {
            int kof = jt * 64 + 8 * (rg >> 2) + (rg & 3) + 4 * hi;
            s0[rg] = (kof > qrow) ? -1e30f : s0[rg];
            s1[rg] = (kof + 32 > qrow) ? -1e30f : s1[rg];
          }
        }

        // ---- online softmax, in-register
        float pm = fmaxf(s0[0], s1[0]);
#pragma unroll
        for (int rg = 1; rg < 16; ++rg) pm = fmaxf(pm, fmaxf(s0[rg], s1[rg]));
        pm = fmaxf(pm, __shfl_xor(pm, 32));
        if (!__all(pm <= m_r + 8.f)) {          // defer-max
          float mn = fmaxf(m_r, pm);
          float corr = exp2f(m_r - mn);
          m_r = mn; l_r *= corr;
#pragma unroll
          for (int rg = 0; rg < 16; ++rg) { o0[rg] *= corr; o1[rg] *= corr; }
        }
        float sum = 0.f;
#pragma unroll
        for (int rg = 0; rg < 16; ++rg) { s0[rg] = exp2f(s0[rg] - m_r); sum += s0[rg]; }
#pragma unroll
        for (int rg = 0; rg < 16; ++rg) { s1[rg] = exp2f(s1[rg] - m_r); sum += s1[rg]; }
        sum += __shfl_xor(sum, 32);
        l_r += sum;

        // ---- PV: O^T[d][q] += Vt[d][k] * Pt[k][q]
#pragma unroll
        for (int s = 0; s < 4; ++s) {
          const f32x16& p = (s >= 2) ? s1 : s0;
          const int base = 8 * (s & 1);
          u32 A0, A1, B0, B1;
          asm("v_cvt_pk_bf16_f32 %0, %1, %2" : "=v"(A0) : "v"(p[base + 0]), "v"(p[base + 1]));
          asm("v_cvt_pk_bf16_f32 %0, %1, %2" : "=v"(A1) : "v"(p[base + 2]), "v"(p[base + 3]));
          asm("v_cvt_pk_bf16_f32 %0, %1, %2" : "=v"(B0) : "v"(p[base + 4]), "v"(p[base + 5]));
          asm("v_cvt_pk_bf16_f32 %0, %1, %2" : "=v"(B1) : "v"(p[base + 6]), "v"(p[base + 7]));
          asm volatile("v_permlane32_swap_b32 %0, %1" : "+v"(A0), "+v"(B0));
          asm volatile("v_permlane32_swap_b32 %0, %1" : "+v"(A1), "+v"(B1));
          u32x4 pw = {A0, A1, B0, B1};
          bf16x8 pf = __builtin_bit_cast(bf16x8, pw);
#pragma unroll
          for (int df = 0; df < 2; ++df) {
            int rr = df * 32 + ql;
            bf16x8 vf = *(const bf16x8*)(Vs[wg][cur] + rr * 64 + (((s * 2 + hi) ^ (rr & 7)) * 8));
            if (df) o1 = __builtin_amdgcn_mfma_f32_32x32x16_bf16(vf, pf, o1, 0, 0, 0);
            else    o0 = __builtin_amdgcn_mfma_f32_32x32x16_bf16(vf, pf, o0, 0, 0, 0);
          }
        }
      }
      __builtin_amdgcn_s_barrier();             // all waves done reading buf
      stageKV(u + 2 < U ? jt + 4 : jt, cur);    // tail: dummy keeps counts
    }
    asm volatile("s_waitcnt vmcnt(0)" ::: "memory");  // drain before reuse
    __syncthreads();

    // ---- merge the two groups' partial (m,l,O) via reused K LDS ----
    // stride-33: bank = (li*33 + idx) % 32 = (li + idx) % 32 -> conflict-free
    if (wg == 1) {
#pragma unroll
      for (int rg = 0; rg < 16; ++rg) {
        Od[li * 33 + rg]      = o0[rg];
        Od[li * 33 + 16 + rg] = o1[rg];
      }
      ml2[li * 3 + 0] = m_r;
      ml2[li * 3 + 1] = l_r;
    }
    __syncthreads();
    if (wg == 0) {
      float m_b = ml2[li * 3 + 0];
      float l_b = ml2[li * 3 + 1];
      float mn = fmaxf(m_r, m_b);
      float ca = exp2f(m_r - mn), cb = exp2f(m_b - mn);
      float rl = 1.f / (l_r * ca + l_b * cb);
      u16* orow = Out + ((size_t)(batch * 2048 + qrow)) * 1024 + h * 64;
#pragma unroll
      for (int df = 0; df < 2; ++df) {
        const f32x16& oo = df ? o1 : o0;
        const float* Op = &Od[li * 33 + df * 16];
#pragma unroll
        for (int b2 = 0; b2 < 4; ++b2) {
          u32 w0, w1;
          float v0 = (oo[4 * b2 + 0] * ca + Op[4 * b2 + 0] * cb) * rl;
          float v1 = (oo[4 * b2 + 1] * ca + Op[4 * b2 + 1] * cb) * rl;
          float v2 = (oo[4 * b2 + 2] * ca + Op[4 * b2 + 2] * cb) * rl;
          float v3 = (oo[4 * b2 + 3] * ca + Op[4 * b2 + 3] * cb) * rl;
          asm("v_cvt_pk_bf16_f32 %0, %1, %2" : "=v"(w0) : "v"(v0), "v"(v1));
          asm("v_cvt_pk_bf16_f32 %0, %1, %2" : "=v"(w1) : "v"(v2), "v"(v3));
          int d0 = df * 32 + b2 * 8 + hi * 4;   // d = 32df + 8b2 + 4hi + e
          u32x2 pr = {w0, w1};
          *(u32x2*)(orow + d0) = pr;
        }
      }
    }
    __syncthreads();                            // merge reads done before next
  }
}

// ---------------- launch ----------------
extern "C" void kernel_launch(void* const* d_in, const int* in_sizes, int n_in,
                              void* d_out, int out_size, void* d_ws, size_t ws_size,
                              hipStream_t stream) {
  (void)in_sizes; (void)n_in; (void)out_size; (void)ws_size;
  const float* query = (const float*)d_in[0];
  const float* key   = (const float*)d_in[1];
  const float* value = (const float*)d_in[2];
  const float* Wq = (const float*)d_in[3];
  const float* bq = (const float*)d_in[4];
  const float* Wk = (const float*)d_in[5];
  const float* bk = (const float*)d_in[6];
  const float* Wv = (const float*)d_in[7];
  const float* bv = (const float*)d_in[8];
  const float* Wo = (const float*)d_in[9];
  const float* bo = (const float*)d_in[10];
  const int* is_causal = (const int*)d_in[11];

  u16* wsp = (u16*)d_ws;                 // ~64 MB of scratch used
  u16* xq  = wsp;                        // 4M elems bf16 [4096,1024]
  u16* xk  = xq  + (4u << 20);
  u16* xv  = xk  + (4u << 20);
  u16* wq  = xv  + (4u << 20);           // 1M elems bf16 [1024,1024]
  u16* wk  = wq  + (1u << 20);
  u16* wv  = wk  + (1u << 20);
  u16* wo  = wv  + (1u << 20);
  u16* Qb  = wo  + (1u << 20);           // 4M, [B,H,S,D], pre-scaled
  u16* Kb  = Qb  + (4u << 20);           // 4M, [B,H,S,D]
  u16* Vtb = Kb  + (4u << 20);           // 4M, [B,H,D,S]
  u16* attn= Vtb + (4u << 20);           // 4M, [B,S,E]

  CvtArgs ca;
  ca.s[0] = query; ca.d[0] = xq; ca.n4[0] = 1 << 20;
  ca.s[1] = key;   ca.d[1] = xk; ca.n4[1] = 1 << 20;
  ca.s[2] = value; ca.d[2] = xv; ca.n4[2] = 1 << 20;
  ca.s[3] = Wq; ca.d[3] = wq; ca.n4[3] = 1 << 18;
  ca.s[4] = Wk; ca.d[4] = wk; ca.n4[4] = 1 << 18;
  ca.s[5] = Wv; ca.d[5] = wv; ca.n4[5] = 1 << 18;
  ca.s[6] = Wo; ca.d[6] = wo; ca.n4[6] = 1 << 18;
  cvt_all<<<dim3(512, 7), 256, 0, stream>>>(ca);

  const float LOG2E = 1.4426950408889634f;
  GemmArgs g1;
  g1.A[0] = xq; g1.W[0] = wq; g1.bias[0] = bq; g1.out[0] = Qb;
  g1.scale[0] = 0.125f * LOG2E; g1.mode[0] = 0;   // Q pre-scaled into exp2 domain
  g1.A[1] = xk; g1.W[1] = wk; g1.bias[1] = bk; g1.out[1] = Kb;
  g1.scale[1] = 1.f; g1.mode[1] = 0;
  g1.A[2] = xv; g1.W[2] = wv; g1.bias[2] = bv; g1.out[2] = Vtb;
  g1.scale[2] = 1.f; g1.mode[2] = 1;              // V stored transposed
  gemm_fused<<<dim3(8, 32, 3), 256, 0, stream>>>(g1);

  attn_kernel<<<dim3(16, 32), 256, 0, stream>>>(Qb, Kb, Vtb, attn, is_causal);

  GemmArgs g2;
  for (int i = 0; i < 3; ++i) {
    g2.A[i] = attn; g2.W[i] = wo; g2.bias[i] = bo; g2.out[i] = d_out;
    g2.scale[i] = 1.f; g2.mode[i] = 2;
  }
  gemm_fused<<<dim3(8, 32, 1), 256, 0, stream>>>(g2);
}